// Round 4
// baseline (332.027 us; speedup 1.0000x reference)
//
#include <hip/hip_runtime.h>
#include <hip/hip_bf16.h>
#include <stdint.h>

#define DIN   4096
#define DOUT  4096
#define MTOT  8192

// old 128^2 fallback geometry
#define BK32   32
#define KT128  (DIN / BK32)
// 256^2 8-phase geometry
#define BK64   64
#define NKT    (DIN / BK64)   // 64 K-tiles

typedef float f32x4  __attribute__((ext_vector_type(4)));
typedef short bf16x8 __attribute__((ext_vector_type(8)));

__device__ __forceinline__ ushort f2bf(float f) {
  __hip_bfloat16 h = __float2bfloat16(f);  // RNE
  ushort r;
  __builtin_memcpy(&r, &h, sizeof(r));
  return r;
}

__device__ __forceinline__ void glds16(const void* g, void* l) {
  __builtin_amdgcn_global_load_lds(
      (__attribute__((address_space(1))) void*)g,
      (__attribute__((address_space(3))) void*)l, 16, 0, 0);
}

// ---------------------------------------------------------------------------
// Kernel 1: per-row alpha (fp64 accumulate) + ternary quantize -> bf16
// ---------------------------------------------------------------------------
__global__ __launch_bounds__(256) void quant_kernel(const float* __restrict__ W,
                                                    ushort* __restrict__ QW) {
  const int row = blockIdx.x;
  const int t = threadIdx.x;
  const float* wr = W + (size_t)row * DIN;

  float4 v[4];
  double s = 0.0;
#pragma unroll
  for (int j = 0; j < 4; ++j) {
    v[j] = reinterpret_cast<const float4*>(wr)[j * 256 + t];
    s += (double)fabsf(v[j].x) + (double)fabsf(v[j].y) +
         (double)fabsf(v[j].z) + (double)fabsf(v[j].w);
  }
#pragma unroll
  for (int off = 32; off > 0; off >>= 1) s += __shfl_down(s, off, 64);

  __shared__ double ssum[4];
  __shared__ float salpha;
  if ((t & 63) == 0) ssum[t >> 6] = s;
  __syncthreads();
  if (t == 0) salpha = (float)((ssum[0] + ssum[1] + ssum[2] + ssum[3]) / (double)DIN);
  __syncthreads();
  const float alpha = salpha;

  ushort4* qo = reinterpret_cast<ushort4*>(QW + (size_t)row * DIN);
#pragma unroll
  for (int j = 0; j < 4; ++j) {
    ushort4 q;
    q.x = v[j].x > alpha ? 0x3F80 : (v[j].x < -alpha ? 0xBF80 : 0);
    q.y = v[j].y > alpha ? 0x3F80 : (v[j].y < -alpha ? 0xBF80 : 0);
    q.z = v[j].z > alpha ? 0x3F80 : (v[j].z < -alpha ? 0xBF80 : 0);
    q.w = v[j].w > alpha ? 0x3F80 : (v[j].w < -alpha ? 0xBF80 : 0);
    qo[j * 256 + t] = q;
  }
}

// ---------------------------------------------------------------------------
// Kernel 2: x fp32 -> bf16
// ---------------------------------------------------------------------------
__global__ __launch_bounds__(256) void cvt_kernel(const float* __restrict__ X,
                                                  ushort* __restrict__ XB, int n4) {
  int idx = blockIdx.x * 256 + threadIdx.x;
  const int stride = gridDim.x * 256;
  for (int i = idx; i < n4; i += stride) {
    float4 v = reinterpret_cast<const float4*>(X)[i];
    ushort4 o;
    o.x = f2bf(v.x); o.y = f2bf(v.y); o.z = f2bf(v.z); o.w = f2bf(v.w);
    reinterpret_cast<ushort4*>(XB)[i] = o;
  }
}

// ---------------------------------------------------------------------------
// Kernel 3: 256x256 8-phase bf16 MFMA GEMM (T2+T3+T4+T5), round-4 schedule:
// register subtiles are issued ONE PHASE EARLY (after the previous phase's
// MFMA cluster) so ds_read latency overlaps MFMA drain + barriers + glds.
//
// Read plan per tile T (quadrants (0,0),(0,1),(1,1),(1,0)):
//   end ph4(T-1): aA(T) [8 rd] + b0cur(T) [4 rd]
//   end ph1(T):   b1(T) [4 rd]
//   end ph2(T):   aB(T) [8 rd]
//   end ph4(T):   aA(T+1) + b0nxt(T+1) (after vmcnt(6) proves T+1 landed)
// glds issue per tile: ph1 B.h1(T+1); ph3 B.h0(T+2); ph4 A.h0+A.h1(T+2).
// Safety: every read drains at the lgkmcnt(0) after its phase's bar1,
// before any wave can issue the overwriting glds (it must pass bar2 first).
// vmcnt ledger: at ph4 wait, exactly 3 halves (6 loads) trail tile T+1.
// ---------------------------------------------------------------------------
__global__ __launch_bounds__(512, 2) void gemm256_kernel(
    const ushort* __restrict__ XB, const ushort* __restrict__ QW,
    const float* __restrict__ scale, const float* __restrict__ bias,
    float* __restrict__ out) {
  __shared__ ushort As[2][16384];  // 32 KB each buf
  __shared__ ushort Bs[2][16384];

  const int t = threadIdx.x;
  const int lane = t & 63;
  const int wid = t >> 6;
  const int wr = wid >> 2, wc = wid & 3;          // 2x4 wave grid
  const int m0 = blockIdx.x * 256;
  const int n0 = blockIdx.y * 256;

  const ushort* ag = XB + (size_t)m0 * DIN;
  const ushort* bg = QW + (size_t)n0 * DIN;

  f32x4 acc[8][4] = {};            // [m-frag 0..7][n-frag 0..3]
  bf16x8 aA[4][2], aB[4][2];       // A halves mh=0 / mh=1
  bf16x8 b0A[2][2], b0B[2][2];     // B half nh=0, tile-parity double buffer
  bf16x8 b1[2][2];                 // B half nh=1

  const int r = lane & 15, kq = lane >> 4;
  const int srow = t >> 3;                         // 0..63
  const int srcc = ((t & 7) ^ ((t >> 3) & 7)) * 8; // inverse-swizzled src chunk (elems)

// issue one half-tile: tile Tt, q: 0=A.h0 1=B.h0 2=A.h1 3=B.h1
#define ISSUE_H(Tt_, q_) do {                                                   \
    const int T_ = (Tt_);                                                       \
    if (T_ < NKT) {                                                             \
      const int q__ = (q_), hf_ = q__ >> 1, bf_ = T_ & 1;                       \
      const ushort* gb_ = (q__ & 1) ? bg : ag;                                  \
      ushort* lb_ = (q__ & 1) ? &Bs[bf_][0] : &As[bf_][0];                      \
      glds16(gb_ + (size_t)(hf_ * 128 + srow) * DIN + T_ * 64 + srcc,           \
             lb_ + hf_ * 8192 + t * 8);                                         \
      glds16(gb_ + (size_t)(hf_ * 128 + 64 + srow) * DIN + T_ * 64 + srcc,      \
             lb_ + hf_ * 8192 + 4096 + t * 8);                                  \
    }                                                                           \
  } while (0)

#define READA_TO(dst_, buf_, mh_) do {                                          \
    _Pragma("unroll")                                                           \
    for (int mi = 0; mi < 4; ++mi) {                                            \
      const int row_ = wr * 128 + ((mh_) * 4 + mi) * 16 + r;                    \
      dst_[mi][0] = *reinterpret_cast<const bf16x8*>(                           \
          &As[buf_][row_ * 64 + ((0 + kq) ^ (r & 7)) * 8]);                     \
      dst_[mi][1] = *reinterpret_cast<const bf16x8*>(                           \
          &As[buf_][row_ * 64 + ((4 + kq) ^ (r & 7)) * 8]);                     \
    }                                                                           \
  } while (0)

#define READB_TO(dst_, buf_, nh_) do {                                          \
    _Pragma("unroll")                                                           \
    for (int ni = 0; ni < 2; ++ni) {                                            \
      const int row_ = wc * 64 + ((nh_) * 2 + ni) * 16 + r;                     \
      dst_[ni][0] = *reinterpret_cast<const bf16x8*>(                           \
          &Bs[buf_][row_ * 64 + ((0 + kq) ^ (r & 7)) * 8]);                     \
      dst_[ni][1] = *reinterpret_cast<const bf16x8*>(                           \
          &Bs[buf_][row_ * 64 + ((4 + kq) ^ (r & 7)) * 8]);                     \
    }                                                                           \
  } while (0)

#define MMA(mh_, nh_, areg_, breg_) do {                                        \
    __builtin_amdgcn_s_setprio(1);                                              \
    _Pragma("unroll")                                                           \
    for (int mi = 0; mi < 4; ++mi) {                                            \
      _Pragma("unroll")                                                         \
      for (int ni = 0; ni < 2; ++ni) {                                          \
        acc[(mh_) * 4 + mi][(nh_) * 2 + ni] =                                   \
            __builtin_amdgcn_mfma_f32_16x16x32_bf16(                            \
                areg_[mi][0], breg_[ni][0],                                     \
                acc[(mh_) * 4 + mi][(nh_) * 2 + ni], 0, 0, 0);                  \
        acc[(mh_) * 4 + mi][(nh_) * 2 + ni] =                                   \
            __builtin_amdgcn_mfma_f32_16x16x32_bf16(                            \
                areg_[mi][1], breg_[ni][1],                                     \
                acc[(mh_) * 4 + mi][(nh_) * 2 + ni], 0, 0, 0);                  \
      }                                                                         \
    }                                                                           \
    __builtin_amdgcn_s_setprio(0);                                              \
  } while (0)

#define BAR() __builtin_amdgcn_s_barrier()
#define LGKM0() asm volatile("s_waitcnt lgkmcnt(0)" ::: "memory")

// one K-tile: buf_ = T&1 (compile-time), b0c_ = this tile's b0, b0n_ = next's
#define TILE(T_, buf_, b0c_, b0n_) do {                                         \
    /* ph1: quadrant (0,0) */                                                   \
    ISSUE_H((T_) + 1, 3);                                                       \
    BAR(); LGKM0();                                                             \
    MMA(0, 0, aA, b0c_);                                                        \
    READB_TO(b1, buf_, 1);                                                      \
    BAR();                                                                      \
    /* ph2: quadrant (0,1) */                                                   \
    BAR(); LGKM0();                                                             \
    MMA(0, 1, aA, b1);                                                          \
    READA_TO(aB, buf_, 1);                                                      \
    BAR();                                                                      \
    /* ph3: quadrant (1,1) */                                                   \
    ISSUE_H((T_) + 2, 1);                                                       \
    BAR(); LGKM0();                                                             \
    MMA(1, 1, aB, b1);                                                          \
    BAR();                                                                      \
    /* ph4: quadrant (1,0) */                                                   \
    ISSUE_H((T_) + 2, 0);                                                       \
    ISSUE_H((T_) + 2, 2);                                                       \
    if ((T_) < NKT - 2)                                                         \
      asm volatile("s_waitcnt vmcnt(6)" ::: "memory");                          \
    else                                                                        \
      asm volatile("s_waitcnt vmcnt(0)" ::: "memory");                          \
    BAR(); LGKM0();                                                             \
    MMA(1, 0, aB, b0c_);                                                        \
    if ((T_) + 1 < NKT) {                                                       \
      READA_TO(aA, (buf_) ^ 1, 0);                                              \
      READB_TO(b0n_, (buf_) ^ 1, 0);                                            \
    }                                                                           \
    BAR();                                                                      \
  } while (0)

  // prologue: tile0 all 4 halves first (vmcnt(6) => tile0's 8 loads landed),
  // then tile1 A.h0, A.h1, B.h0 (B.h1(1) is issued in tile0 ph1).
  ISSUE_H(0, 0); ISSUE_H(0, 1); ISSUE_H(0, 2); ISSUE_H(0, 3);
  ISSUE_H(1, 0); ISSUE_H(1, 2); ISSUE_H(1, 1);
  asm volatile("s_waitcnt vmcnt(6)" ::: "memory");
  __builtin_amdgcn_s_barrier();
  // prologue register reads for tile 0, phase 1
  READA_TO(aA, 0, 0);
  READB_TO(b0A, 0, 0);

  for (int T = 0; T < NKT; T += 2) {
    TILE(T, 0, b0A, b0B);
    TILE(T + 1, 1, b0B, b0A);
  }

  // epilogue: C/D lane map col=lane&15, row=(lane>>4)*4+e (m89-verified)
  const int q4 = lane >> 4;
#pragma unroll
  for (int ni = 0; ni < 4; ++ni) {
    const int col = n0 + wc * 64 + ni * 16 + r;
    const float sc = scale[col];
    const float bs = bias[col];
#pragma unroll
    for (int mi = 0; mi < 8; ++mi) {
      const int row = m0 + wr * 128 + mi * 16 + q4 * 4;
#pragma unroll
      for (int e = 0; e < 4; ++e)
        out[(size_t)(row + e) * DOUT + col] = acc[mi][ni][e] * sc + bs;
    }
  }
#undef ISSUE_H
#undef READA_TO
#undef READB_TO
#undef MMA
#undef BAR
#undef LGKM0
#undef TILE
}

// ---------------------------------------------------------------------------
// Fallback (small workspace): 128^2 reg-staged kernel from round 1
// ---------------------------------------------------------------------------
__global__ __launch_bounds__(256, 2) void gemm128_kernel(
    const float* __restrict__ X, const ushort* __restrict__ QW,
    const float* __restrict__ scale, const float* __restrict__ bias,
    float* __restrict__ out) {
  __shared__ ushort Al[2][128 * BK32];
  __shared__ ushort Bl[2][128 * BK32];

  const int t = threadIdx.x;
  const int lane = t & 63;
  const int wid = t >> 6;
  const int wr = wid >> 1, wc = wid & 1;
  const int m0 = blockIdx.x * 128;
  const int n0 = blockIdx.y * 128;

  f32x4 acc[4][4] = {};
  const ushort* bg = QW + (size_t)n0 * DIN;
  const float*  ag = X  + (size_t)m0 * DIN;
  float4 areg[4];

  auto stageB = [&](int kt, int buf) {
    const ushort* src = bg + kt * BK32;
#pragma unroll
    for (int i = 0; i < 2; ++i)
      glds16(src + (size_t)(i * 64 + (t >> 2)) * DIN + (t & 3) * 8,
             &Bl[buf][(i * 256 + t) * 8]);
  };
  auto loadA_reg = [&](int kt) {
#pragma unroll
    for (int j = 0; j < 4; ++j)
      areg[j] = *reinterpret_cast<const float4*>(
          ag + (size_t)(j * 32 + (t >> 3)) * DIN + kt * BK32 + (t & 7) * 4);
  };
  auto writeA_reg = [&](int buf) {
#pragma unroll
    for (int j = 0; j < 4; ++j) {
      ushort4 o;
      o.x = f2bf(areg[j].x); o.y = f2bf(areg[j].y);
      o.z = f2bf(areg[j].z); o.w = f2bf(areg[j].w);
      *reinterpret_cast<ushort4*>(&Al[buf][(j * 256 + t) * 4]) = o;
    }
  };
  auto compute = [&](int buf) {
    const int r = lane & 15;
    const int kq = lane >> 4;
    bf16x8 af[4], bfr[4];
#pragma unroll
    for (int mi = 0; mi < 4; ++mi)
      af[mi] = *reinterpret_cast<const bf16x8*>(
          &Al[buf][(wr * 64 + mi * 16 + r) * BK32 + kq * 8]);
#pragma unroll
    for (int ni = 0; ni < 4; ++ni)
      bfr[ni] = *reinterpret_cast<const bf16x8*>(
          &Bl[buf][(wc * 64 + ni * 16 + r) * BK32 + kq * 8]);
#pragma unroll
    for (int mi = 0; mi < 4; ++mi)
#pragma unroll
      for (int ni = 0; ni < 4; ++ni)
        acc[mi][ni] = __builtin_amdgcn_mfma_f32_16x16x32_bf16(
            af[mi], bfr[ni], acc[mi][ni], 0, 0, 0);
  };

  loadA_reg(0);
  stageB(0, 0);
  writeA_reg(0);
  __syncthreads();

  int cur = 0;
  for (int kt = 0; kt < KT128; ++kt) {
    if (kt + 1 < KT128) {
      loadA_reg(kt + 1);
      stageB(kt + 1, cur ^ 1);
    }
    compute(cur);
    if (kt + 1 < KT128) {
      writeA_reg(cur ^ 1);
      __syncthreads();
      cur ^= 1;
    }
  }

  const int r = lane & 15;
  const int q4 = lane >> 4;
#pragma unroll
  for (int ni = 0; ni < 4; ++ni) {
    const int col = n0 + wc * 64 + ni * 16 + r;
    const float sc = scale[col];
    const float bs = bias[col];
#pragma unroll
    for (int mi = 0; mi < 4; ++mi) {
      const int row = m0 + wr * 64 + mi * 16 + q4 * 4;
#pragma unroll
      for (int e = 0; e < 4; ++e)
        out[(size_t)(row + e) * DOUT + col] = acc[mi][ni][e] * sc + bs;
    }
  }
}

extern "C" void kernel_launch(void* const* d_in, const int* in_sizes, int n_in,
                              void* d_out, int out_size, void* d_ws, size_t ws_size,
                              hipStream_t stream) {
  const float* X     = (const float*)d_in[0];
  const float* W     = (const float*)d_in[1];
  const float* scale = (const float*)d_in[2];
  const float* bias  = (const float*)d_in[3];
  float* out = (float*)d_out;

  const size_t qw_bytes = (size_t)DOUT * DIN * sizeof(ushort);  // 32 MB
  const size_t xb_bytes = (size_t)MTOT * DIN * sizeof(ushort);  // 64 MB
  ushort* QW = (ushort*)d_ws;
  ushort* XB = (ushort*)((char*)d_ws + qw_bytes);

  quant_kernel<<<DOUT, 256, 0, stream>>>(W, QW);

  if (ws_size >= qw_bytes + xb_bytes) {
    cvt_kernel<<<2048, 256, 0, stream>>>(X, XB, MTOT * DIN / 4);
    dim3 grid(MTOT / 256, DOUT / 256);
    gemm256_kernel<<<grid, 512, 0, stream>>>(XB, QW, scale, bias, out);
  } else {
    dim3 grid(MTOT / 128, DOUT / 128);
    gemm128_kernel<<<grid, 256, 0, stream>>>(X, QW, scale, bias, out);
  }
}

// Round 6
// 318.493 us; speedup vs baseline: 1.0425x; 1.0425x over previous
//
#include <hip/hip_runtime.h>
#include <hip/hip_bf16.h>
#include <stdint.h>

#define DIN   4096
#define DOUT  4096
#define MTOT  8192

// old 128^2 fallback geometry
#define BK32   32
#define KT128  (DIN / BK32)
// 256^2 8-phase geometry
#define BK64   64
#define NKT    (DIN / BK64)   // 64 K-tiles

typedef float f32x4  __attribute__((ext_vector_type(4)));
typedef short bf16x8 __attribute__((ext_vector_type(8)));

__device__ __forceinline__ ushort f2bf(float f) {
  __hip_bfloat16 h = __float2bfloat16(f);  // RNE
  ushort r;
  __builtin_memcpy(&r, &h, sizeof(r));
  return r;
}

__device__ __forceinline__ void glds16(const void* g, void* l) {
  __builtin_amdgcn_global_load_lds(
      (__attribute__((address_space(1))) void*)g,
      (__attribute__((address_space(3))) void*)l, 16, 0, 0);
}

// ---------------------------------------------------------------------------
// Kernel 1: per-row alpha (fp64 accumulate) + ternary quantize -> bf16
// ---------------------------------------------------------------------------
__global__ __launch_bounds__(256) void quant_kernel(const float* __restrict__ W,
                                                    ushort* __restrict__ QW) {
  const int row = blockIdx.x;
  const int t = threadIdx.x;
  const float* wr = W + (size_t)row * DIN;

  float4 v[4];
  double s = 0.0;
#pragma unroll
  for (int j = 0; j < 4; ++j) {
    v[j] = reinterpret_cast<const float4*>(wr)[j * 256 + t];
    s += (double)fabsf(v[j].x) + (double)fabsf(v[j].y) +
         (double)fabsf(v[j].z) + (double)fabsf(v[j].w);
  }
#pragma unroll
  for (int off = 32; off > 0; off >>= 1) s += __shfl_down(s, off, 64);

  __shared__ double ssum[4];
  __shared__ float salpha;
  if ((t & 63) == 0) ssum[t >> 6] = s;
  __syncthreads();
  if (t == 0) salpha = (float)((ssum[0] + ssum[1] + ssum[2] + ssum[3]) / (double)DIN);
  __syncthreads();
  const float alpha = salpha;

  ushort4* qo = reinterpret_cast<ushort4*>(QW + (size_t)row * DIN);
#pragma unroll
  for (int j = 0; j < 4; ++j) {
    ushort4 q;
    q.x = v[j].x > alpha ? 0x3F80 : (v[j].x < -alpha ? 0xBF80 : 0);
    q.y = v[j].y > alpha ? 0x3F80 : (v[j].y < -alpha ? 0xBF80 : 0);
    q.z = v[j].z > alpha ? 0x3F80 : (v[j].z < -alpha ? 0xBF80 : 0);
    q.w = v[j].w > alpha ? 0x3F80 : (v[j].w < -alpha ? 0xBF80 : 0);
    qo[j * 256 + t] = q;
  }
}

// ---------------------------------------------------------------------------
// Kernel 2: x fp32 -> bf16
// ---------------------------------------------------------------------------
__global__ __launch_bounds__(256) void cvt_kernel(const float* __restrict__ X,
                                                  ushort* __restrict__ XB, int n4) {
  int idx = blockIdx.x * 256 + threadIdx.x;
  const int stride = gridDim.x * 256;
  for (int i = idx; i < n4; i += stride) {
    float4 v = reinterpret_cast<const float4*>(X)[i];
    ushort4 o;
    o.x = f2bf(v.x); o.y = f2bf(v.y); o.z = f2bf(v.z); o.w = f2bf(v.w);
    reinterpret_cast<ushort4*>(XB)[i] = o;
  }
}

// ---------------------------------------------------------------------------
// Kernel 3: 256x256 8-phase bf16 MFMA GEMM, round-6 corrected even-read
// schedule. Quadrants (0,0),(1,0),(1,1),(0,1); reads in-phase 8/8/4/4.
//
// REGION FACTS (round-5 post-mortem): staged halves are row-ranges
// (h0=rows 0..127, h1=128..255). A wave reads b0 AND b1 from the SAME
// staged half (wc<2 -> h0, wc>=2 -> h1); similarly aA and aB from the same
// A half (wr=0 -> h0, wr=1 -> h1). Therefore:
//   - ANY A-half overwrite of As[buf] must be issued after ph2 (aB drains)
//   - ANY B-half overwrite of Bs[buf] must be issued after ph3 (b1 drains)
// Schedule:
//   ph1: read aA(T) [8];                    MMA(0,0)=aA*b0
//   ph2: read aB(T) [8];                    MMA(1,0)=aB*b0
//   ph3: read b1(T) [4]; stage A.h0+A.h1(T+2); MMA(1,1)=aB*b1
//   ph4: stage B.h0+B.h1(T+2); vmcnt(8); BAR; lgkm0; read b0(T+1) [4];
//        MMA(0,1)=aA*b1; lgkm0; BAR
// Overwrite audit: A(T+2)@ph3 — aA drained ph1, aB drained ph2 (each wave's
// lgkm0 precedes its ph BAR2; all waves crossed ph2 BAR2 before any wave
// reaches ph3). B(T+2)@ph4 — b1 drained ph3; b0c was read at (T-1).ph4 and
// drained at its trailing lgkm0 before that phase's BAR2. b0n@ph4 reads
// Bs[buf^1], next overwritten only at (T+1).ph4. All safe.
// vmcnt ledger (stream order per tile: A0,A1@ph3, B0,B1@ph4; prologue
// mirrors A0,A1,B0,B1 x tiles 0,1): at T.ph4 wait, exactly 4 halves
// (8 loads) of tile T+2 trail tile T+1's last load -> vmcnt(8) == tile T+1
// fully landed. vmcnt(0) for T >= NKT-2.
// ---------------------------------------------------------------------------
__global__ __launch_bounds__(512, 2) void gemm256_kernel(
    const ushort* __restrict__ XB, const ushort* __restrict__ QW,
    const float* __restrict__ scale, const float* __restrict__ bias,
    float* __restrict__ out) {
  __shared__ ushort As[2][16384];  // 32 KB each buf
  __shared__ ushort Bs[2][16384];

  const int t = threadIdx.x;
  const int lane = t & 63;
  const int wid = t >> 6;
  const int wr = wid >> 2, wc = wid & 3;          // 2x4 wave grid
  const int m0 = blockIdx.x * 256;
  const int n0 = blockIdx.y * 256;

  const ushort* ag = XB + (size_t)m0 * DIN;
  const ushort* bg = QW + (size_t)n0 * DIN;

  f32x4 acc[8][4] = {};            // [m-frag 0..7][n-frag 0..3]
  bf16x8 aA[4][2], aB[4][2];       // A halves mh=0 / mh=1
  bf16x8 b0A[2][2], b0B[2][2];     // B half nh=0, tile-parity double buffer
  bf16x8 b1[2][2];                 // B half nh=1

  const int r = lane & 15, kq = lane >> 4;
  const int srow = t >> 3;                         // 0..63
  const int srcc = ((t & 7) ^ ((t >> 3) & 7)) * 8; // inverse-swizzled src chunk (elems)

// issue one half-tile: tile Tt, q: 0=A.h0 1=B.h0 2=A.h1 3=B.h1
#define ISSUE_H(Tt_, q_) do {                                                   \
    const int T_ = (Tt_);                                                       \
    if (T_ < NKT) {                                                             \
      const int q__ = (q_), hf_ = q__ >> 1, bf_ = T_ & 1;                       \
      const ushort* gb_ = (q__ & 1) ? bg : ag;                                  \
      ushort* lb_ = (q__ & 1) ? &Bs[bf_][0] : &As[bf_][0];                      \
      glds16(gb_ + (size_t)(hf_ * 128 + srow) * DIN + T_ * 64 + srcc,           \
             lb_ + hf_ * 8192 + t * 8);                                         \
      glds16(gb_ + (size_t)(hf_ * 128 + 64 + srow) * DIN + T_ * 64 + srcc,      \
             lb_ + hf_ * 8192 + 4096 + t * 8);                                  \
    }                                                                           \
  } while (0)

#define READA_TO(dst_, buf_, mh_) do {                                          \
    _Pragma("unroll")                                                           \
    for (int mi = 0; mi < 4; ++mi) {                                            \
      const int row_ = wr * 128 + ((mh_) * 4 + mi) * 16 + r;                    \
      dst_[mi][0] = *reinterpret_cast<const bf16x8*>(                           \
          &As[buf_][row_ * 64 + ((0 + kq) ^ (r & 7)) * 8]);                     \
      dst_[mi][1] = *reinterpret_cast<const bf16x8*>(                           \
          &As[buf_][row_ * 64 + ((4 + kq) ^ (r & 7)) * 8]);                     \
    }                                                                           \
  } while (0)

#define READB_TO(dst_, buf_, nh_) do {                                          \
    _Pragma("unroll")                                                           \
    for (int ni = 0; ni < 2; ++ni) {                                            \
      const int row_ = wc * 64 + ((nh_) * 2 + ni) * 16 + r;                     \
      dst_[ni][0] = *reinterpret_cast<const bf16x8*>(                           \
          &Bs[buf_][row_ * 64 + ((0 + kq) ^ (r & 7)) * 8]);                     \
      dst_[ni][1] = *reinterpret_cast<const bf16x8*>(                           \
          &Bs[buf_][row_ * 64 + ((4 + kq) ^ (r & 7)) * 8]);                     \
    }                                                                           \
  } while (0)

#define MMA(mh_, nh_, areg_, breg_) do {                                        \
    __builtin_amdgcn_s_setprio(1);                                              \
    _Pragma("unroll")                                                           \
    for (int mi = 0; mi < 4; ++mi) {                                            \
      _Pragma("unroll")                                                         \
      for (int ni = 0; ni < 2; ++ni) {                                          \
        acc[(mh_) * 4 + mi][(nh_) * 2 + ni] =                                   \
            __builtin_amdgcn_mfma_f32_16x16x32_bf16(                            \
                areg_[mi][0], breg_[ni][0],                                     \
                acc[(mh_) * 4 + mi][(nh_) * 2 + ni], 0, 0, 0);                  \
        acc[(mh_) * 4 + mi][(nh_) * 2 + ni] =                                   \
            __builtin_amdgcn_mfma_f32_16x16x32_bf16(                            \
                areg_[mi][1], breg_[ni][1],                                     \
                acc[(mh_) * 4 + mi][(nh_) * 2 + ni], 0, 0, 0);                  \
      }                                                                         \
    }                                                                           \
    __builtin_amdgcn_s_setprio(0);                                              \
  } while (0)

#define BAR() __builtin_amdgcn_s_barrier()
#define LGKM0() asm volatile("s_waitcnt lgkmcnt(0)" ::: "memory")

// one K-tile: buf_ = T&1 (compile-time), b0c_ = this tile's b0, b0n_ = next's
#define TILE(T_, buf_, b0c_, b0n_) do {                                         \
    /* ph1: (0,0) */                                                            \
    READA_TO(aA, buf_, 0);                                                      \
    BAR(); LGKM0();                                                             \
    MMA(0, 0, aA, b0c_);                                                        \
    BAR();                                                                      \
    /* ph2: (1,0) */                                                            \
    READA_TO(aB, buf_, 1);                                                      \
    BAR(); LGKM0();                                                             \
    MMA(1, 0, aB, b0c_);                                                        \
    BAR();                                                                      \
    /* ph3: (1,1) — A(T+2) overwrite legal: aA drained ph1, aB drained ph2 */   \
    READB_TO(b1, buf_, 1);                                                      \
    ISSUE_H((T_) + 2, 0);                                                       \
    ISSUE_H((T_) + 2, 2);                                                       \
    BAR(); LGKM0();                                                             \
    MMA(1, 1, aB, b1);                                                          \
    BAR();                                                                      \
    /* ph4: (0,1) — B(T+2) overwrite legal: b1 drained ph3, b0c at (T-1).ph4 */ \
    ISSUE_H((T_) + 2, 1);                                                       \
    ISSUE_H((T_) + 2, 3);                                                       \
    if ((T_) < NKT - 2)                                                         \
      asm volatile("s_waitcnt vmcnt(8)" ::: "memory");                          \
    else                                                                        \
      asm volatile("s_waitcnt vmcnt(0)" ::: "memory");                          \
    BAR(); LGKM0();                                                             \
    if ((T_) + 1 < NKT) { READB_TO(b0n_, (buf_) ^ 1, 0); }                      \
    MMA(0, 1, aA, b1);                                                          \
    LGKM0();  /* drain b0n reads before BAR2: overwrite-safety anchor */        \
    BAR();                                                                      \
  } while (0)

  // prologue: tiles 0 and 1, per-tile order A0,A1,B0,B1 (16 loads),
  // matching the steady-state stream order for the vmcnt ledger.
  ISSUE_H(0, 0); ISSUE_H(0, 2); ISSUE_H(0, 1); ISSUE_H(0, 3);
  ISSUE_H(1, 0); ISSUE_H(1, 2); ISSUE_H(1, 1); ISSUE_H(1, 3);
  asm volatile("s_waitcnt vmcnt(8)" ::: "memory");  // tile 0 fully landed
  __builtin_amdgcn_s_barrier();
  READB_TO(b0A, 0, 0);   // b0 of tile 0
  LGKM0();               // drain before first overwrite issue (T0.ph3/ph4)
  __builtin_amdgcn_s_barrier();

  for (int T = 0; T < NKT; T += 2) {
    TILE(T, 0, b0A, b0B);
    TILE(T + 1, 1, b0B, b0A);
  }

  // epilogue: C/D lane map col=lane&15, row=(lane>>4)*4+e (m89-verified)
  const int q4 = lane >> 4;
#pragma unroll
  for (int ni = 0; ni < 4; ++ni) {
    const int col = n0 + wc * 64 + ni * 16 + r;
    const float sc = scale[col];
    const float bs = bias[col];
#pragma unroll
    for (int mi = 0; mi < 8; ++mi) {
      const int row = m0 + wr * 128 + mi * 16 + q4 * 4;
#pragma unroll
      for (int e = 0; e < 4; ++e)
        out[(size_t)(row + e) * DOUT + col] = acc[mi][ni][e] * sc + bs;
    }
  }
#undef ISSUE_H
#undef READA_TO
#undef READB_TO
#undef MMA
#undef BAR
#undef LGKM0
#undef TILE
}

// ---------------------------------------------------------------------------
// Fallback (small workspace): 128^2 reg-staged kernel from round 1
// ---------------------------------------------------------------------------
__global__ __launch_bounds__(256, 2) void gemm128_kernel(
    const float* __restrict__ X, const ushort* __restrict__ QW,
    const float* __restrict__ scale, const float* __restrict__ bias,
    float* __restrict__ out) {
  __shared__ ushort Al[2][128 * BK32];
  __shared__ ushort Bl[2][128 * BK32];

  const int t = threadIdx.x;
  const int lane = t & 63;
  const int wid = t >> 6;
  const int wr = wid >> 1, wc = wid & 1;
  const int m0 = blockIdx.x * 128;
  const int n0 = blockIdx.y * 128;

  f32x4 acc[4][4] = {};
  const ushort* bg = QW + (size_t)n0 * DIN;
  const float*  ag = X  + (size_t)m0 * DIN;
  float4 areg[4];

  auto stageB = [&](int kt, int buf) {
    const ushort* src = bg + kt * BK32;
#pragma unroll
    for (int i = 0; i < 2; ++i)
      glds16(src + (size_t)(i * 64 + (t >> 2)) * DIN + (t & 3) * 8,
             &Bl[buf][(i * 256 + t) * 8]);
  };
  auto loadA_reg = [&](int kt) {
#pragma unroll
    for (int j = 0; j < 4; ++j)
      areg[j] = *reinterpret_cast<const float4*>(
          ag + (size_t)(j * 32 + (t >> 3)) * DIN + kt * BK32 + (t & 7) * 4);
  };
  auto writeA_reg = [&](int buf) {
#pragma unroll
    for (int j = 0; j < 4; ++j) {
      ushort4 o;
      o.x = f2bf(areg[j].x); o.y = f2bf(areg[j].y);
      o.z = f2bf(areg[j].z); o.w = f2bf(areg[j].w);
      *reinterpret_cast<ushort4*>(&Al[buf][(j * 256 + t) * 4]) = o;
    }
  };
  auto compute = [&](int buf) {
    const int r = lane & 15;
    const int kq = lane >> 4;
    bf16x8 af[4], bfr[4];
#pragma unroll
    for (int mi = 0; mi < 4; ++mi)
      af[mi] = *reinterpret_cast<const bf16x8*>(
          &Al[buf][(wr * 64 + mi * 16 + r) * BK32 + kq * 8]);
#pragma unroll
    for (int ni = 0; ni < 4; ++ni)
      bfr[ni] = *reinterpret_cast<const bf16x8*>(
          &Bl[buf][(wc * 64 + ni * 16 + r) * BK32 + kq * 8]);
#pragma unroll
    for (int mi = 0; mi < 4; ++mi)
#pragma unroll
      for (int ni = 0; ni < 4; ++ni)
        acc[mi][ni] = __builtin_amdgcn_mfma_f32_16x16x32_bf16(
            af[mi], bfr[ni], acc[mi][ni], 0, 0, 0);
  };

  loadA_reg(0);
  stageB(0, 0);
  writeA_reg(0);
  __syncthreads();

  int cur = 0;
  for (int kt = 0; kt < KT128; ++kt) {
    if (kt + 1 < KT128) {
      loadA_reg(kt + 1);
      stageB(kt + 1, cur ^ 1);
    }
    compute(cur);
    if (kt + 1 < KT128) {
      writeA_reg(cur ^ 1);
      __syncthreads();
      cur ^= 1;
    }
  }

  const int r = lane & 15;
  const int q4 = lane >> 4;
#pragma unroll
  for (int ni = 0; ni < 4; ++ni) {
    const int col = n0 + wc * 64 + ni * 16 + r;
    const float sc = scale[col];
    const float bs = bias[col];
#pragma unroll
    for (int mi = 0; mi < 4; ++mi) {
      const int row = m0 + wr * 64 + mi * 16 + q4 * 4;
#pragma unroll
      for (int e = 0; e < 4; ++e)
        out[(size_t)(row + e) * DOUT + col] = acc[mi][ni][e] * sc + bs;
    }
  }
}

extern "C" void kernel_launch(void* const* d_in, const int* in_sizes, int n_in,
                              void* d_out, int out_size, void* d_ws, size_t ws_size,
                              hipStream_t stream) {
  const float* X     = (const float*)d_in[0];
  const float* W     = (const float*)d_in[1];
  const float* scale = (const float*)d_in[2];
  const float* bias  = (const float*)d_in[3];
  float* out = (float*)d_out;

  const size_t qw_bytes = (size_t)DOUT * DIN * sizeof(ushort);  // 32 MB
  const size_t xb_bytes = (size_t)MTOT * DIN * sizeof(ushort);  // 64 MB
  ushort* QW = (ushort*)d_ws;
  ushort* XB = (ushort*)((char*)d_ws + qw_bytes);

  quant_kernel<<<DOUT, 256, 0, stream>>>(W, QW);

  if (ws_size >= qw_bytes + xb_bytes) {
    cvt_kernel<<<2048, 256, 0, stream>>>(X, XB, MTOT * DIN / 4);
    dim3 grid(MTOT / 256, DOUT / 256);
    gemm256_kernel<<<grid, 512, 0, stream>>>(XB, QW, scale, bias, out);
  } else {
    dim3 grid(MTOT / 128, DOUT / 128);
    gemm128_kernel<<<grid, 256, 0, stream>>>(X, QW, scale, bias, out);
  }
}